// Round 8
// baseline (293.992 us; speedup 1.0000x reference)
//
#include <hip/hip_runtime.h>
#include <hip/hip_bf16.h>
#include <math.h>

#define Bb 8
#define Nn 96
#define Dd 256
#define BN (Bb*Nn)      /* 768 */
#define MT (BN*Nn)      /* 73728 edge rows */
#define PI_OVER_CUTOFF 0.62831853071795864769f  /* pi/5 */

#define QKV_ROWS    8
#define QKV_BLOCKS  ((BN / QKV_ROWS) * 3)  /* 288, dispatched FIRST (latency-chained) */
#define WT_BLOCKS   512
#define PREP_BLOCKS (MT * Dd / (256*16))   /* 4608: 16 elts/thread streaming */

typedef short short8 __attribute__((ext_vector_type(8)));
typedef float f32x4  __attribute__((ext_vector_type(4)));

// fast silu: v_exp_f32 + v_rcp_f32 are ~1ulp; inputs already bf16-quantized.
__device__ __forceinline__ float silu_f(float x){
    return x * __builtin_amdgcn_rcpf(1.0f + __expf(-x));
}

__device__ __forceinline__ short f2bf(float f){
    __hip_bfloat16 h = __float2bfloat16(f);
    return __builtin_bit_cast(short, h);
}
__device__ __forceinline__ float bf2f(unsigned short u){
    union { unsigned uu; float ff; } a; a.uu = ((unsigned)u) << 16; return a.ff;
}

// async global->LDS, 16B per lane. LDS dest = base + lane*16 (wave-uniform base).
__device__ __forceinline__ void gll16(short* lds, const unsigned short* g){
    __builtin_amdgcn_global_load_lds(
        (const __attribute__((address_space(1))) unsigned int*)g,
        (__attribute__((address_space(3))) unsigned int*)lds, 16, 0, 0);
}

// ---------------- Kernel 1: setup = qkv (8-row GEMV, first) + wt + prep (nt stream) ----------------
__global__ __launch_bounds__(256) void setup_kernel(
    const float* __restrict__ edge, unsigned short* __restrict__ ebf,
    const float* __restrict__ Wdk, const float* __restrict__ Wea,
    short* __restrict__ Wtdk, short* __restrict__ Wtea,
    const float* __restrict__ x,
    const float* __restrict__ Wq, const float* __restrict__ bq,
    const float* __restrict__ Wk, const float* __restrict__ bk,
    const float* __restrict__ Wv, const float* __restrict__ bv,
    float* __restrict__ qo, float* __restrict__ ko, float* __restrict__ vo)
{
    const int blk = blockIdx.x;
    const int tid = threadIdx.x;

    if (blk < QKV_BLOCKS) {
        // ---- qkv: 8 rows/block. 4 W loads feed 32 FMAs (8 indep chains) per iter. ----
        __shared__ float xs[QKV_ROWS][Dd];
        const int idx = blk;
        const int sel = idx % 3;
        const int r0  = (idx / 3) * QKV_ROWS;
        const float* W  = sel == 0 ? Wq : (sel == 1 ? Wk : Wv);
        const float* bb = sel == 0 ? bq : (sel == 1 ? bk : bv);
        float*       ou = sel == 0 ? qo : (sel == 1 ? ko : vo);

        #pragma unroll
        for (int i = 0; i < QKV_ROWS; ++i) xs[i][tid] = x[(size_t)(r0 + i) * Dd + tid];
        __syncthreads();

        float a[QKV_ROWS];
        const float bvv = bb[tid];
        #pragma unroll
        for (int i = 0; i < QKV_ROWS; ++i) a[i] = bvv;

        for (int k4 = 0; k4 < 64; ++k4) {
            const float w0 = W[(size_t)(k4 * 4 + 0) * Dd + tid];
            const float w1 = W[(size_t)(k4 * 4 + 1) * Dd + tid];
            const float w2 = W[(size_t)(k4 * 4 + 2) * Dd + tid];
            const float w3 = W[(size_t)(k4 * 4 + 3) * Dd + tid];
            #pragma unroll
            for (int i = 0; i < QKV_ROWS; ++i) {
                const float4 e = *(const float4*)&xs[i][k4 * 4];
                a[i] = fmaf(e.x, w0, fmaf(e.y, w1, fmaf(e.z, w2, fmaf(e.w, w3, a[i]))));
            }
        }
        #pragma unroll
        for (int i = 0; i < QKV_ROWS; ++i)
            ou[(size_t)(r0 + i) * Dd + tid] = a[i];
        return;
    }
    if (blk < QKV_BLOCKS + WT_BLOCKS) {
        // ---- Wt = bf16(W^T): coalesced READ, scattered 2B write (fire-and-forget) ----
        const int o   = (blk - QKV_BLOCKS) * 256 + tid;
        const int sel = o >> 16;
        const int r   = o & 65535;           // r = k*256 + n (source-linear)
        const float* src = sel ? Wea : Wdk;
        short*       dst = sel ? Wtea : Wtdk;
        dst[(r & 255) * 256 + (r >> 8)] = f2bf(src[r]);
        return;
    }

    // ---- prep: edge fp32 -> bf16, 16 elts/thread, non-temporal reads (dead after use) ----
    const size_t idx = ((size_t)(blk - QKV_BLOCKS - WT_BLOCKS) * 256 + tid) * 16;
    const f32x4 a = __builtin_nontemporal_load((const f32x4*)(edge + idx));
    const f32x4 b = __builtin_nontemporal_load((const f32x4*)(edge + idx + 4));
    const f32x4 c = __builtin_nontemporal_load((const f32x4*)(edge + idx + 8));
    const f32x4 d = __builtin_nontemporal_load((const f32x4*)(edge + idx + 12));
    short8 s0, s1;
    s0[0]=f2bf(a[0]); s0[1]=f2bf(a[1]); s0[2]=f2bf(a[2]); s0[3]=f2bf(a[3]);
    s0[4]=f2bf(b[0]); s0[5]=f2bf(b[1]); s0[6]=f2bf(b[2]); s0[7]=f2bf(b[3]);
    s1[0]=f2bf(c[0]); s1[1]=f2bf(c[1]); s1[2]=f2bf(c[2]); s1[3]=f2bf(c[3]);
    s1[4]=f2bf(d[0]); s1[5]=f2bf(d[1]); s1[6]=f2bf(d[2]); s1[7]=f2bf(d[3]);
    *(short8*)(ebf + idx)     = s0;
    *(short8*)(ebf + idx + 8) = s1;
}

// ---------------- Kernel 2: fused dk-GEMM + attention + ea-GEMM (As tiles & acc reused) ----------------
// 512 thr = 8 waves; wave w owns cols [w*32,+32) = head w. 96 rows (m), K=256 staged once.
// Phase order: stage -> barrier -> dk GEMM -> attn epilogue (VALU) -> ea GEMM (same As,
// same acc regs re-zeroed) -> ea epilogue (silu -> eab bf16). Late-wave MFMA overlaps
// early-wave VALU (separate pipes); attn/t stores drain under the ea GEMM.
__global__ __launch_bounds__(512, 4) void dk_attn_kernel(
    const unsigned short* __restrict__ ebf,
    const short* __restrict__ Wt, const short* __restrict__ Wte,
    const float* __restrict__ bdk, const float* __restrict__ bea,
    const float* __restrict__ q, const float* __restrict__ kmat, const float* __restrict__ vmat,
    const int* __restrict__ mask, const float* __restrict__ dist, const float* __restrict__ vec,
    float* __restrict__ attn_out, float* __restrict__ t_out, float* __restrict__ sv_out,
    unsigned short* __restrict__ eab)
{
    __shared__ short As[2 * 96 * 128];   // 48 KB, both K-chunks resident
    __shared__ float scl[Nn];
    __shared__ float vcs[Nn][3];
    __shared__ int   mks[Nn];

    const int bn   = blockIdx.x;
    const int b    = bn / Nn;
    const int tid  = threadIdx.x;
    const int lane = tid & 63;
    const int w    = tid >> 6;
    const int l15  = lane & 15;
    const int lq   = lane >> 4;

    if (tid < Nn) {
        const int   mm = mask[(size_t)bn * Nn + tid];
        const float di = dist[(size_t)bn * Nn + tid];
        const float s  = (di < 5.0f) ? 0.5f * (__cosf(di * PI_OVER_CUTOFF) + 1.0f) : 0.0f;
        scl[tid] = mm ? 0.0f : s;
        mks[tid] = mm;
    }
    for (int j = tid; j < Nn * 3; j += 512)
        (&vcs[0][0])[j] = vec[(size_t)bn * Nn * 3 + j];

    const int dj0 = w * 32 + l15, dj1 = dj0 + 16;
    const float qd0 = q[(size_t)bn * Dd + dj0], qd1 = q[(size_t)bn * Dd + dj1];
    const float bv0 = bdk[dj0], bv1 = bdk[dj1];

    f32x4 acc[6][2];
    #pragma unroll
    for (int i = 0; i < 6; ++i) { acc[i][0] = (f32x4){0.f,0.f,0.f,0.f}; acc[i][1] = (f32x4){0.f,0.f,0.f,0.f}; }

    const unsigned short* ebase = ebf + (size_t)bn * Nn * Dd;
    const int srow = (lane >> 4);          // 0..3 within chunk
    const int cs   = lane & 15;            // stored segment

    // stage BOTH K-chunks, then one barrier
    #pragma unroll
    for (int kt = 0; kt < 2; ++kt) {
        #pragma unroll
        for (int u = 0; u < 3; ++u) {
            const int chunk = w * 3 + u;           // 0..23, 4 rows each
            const int r     = chunk * 4 + srow;
            const int gseg  = cs ^ (r & 7);
            gll16(As + kt * (96*128) + chunk * 512,
                  ebase + (size_t)r * Dd + kt * 128 + gseg * 8);
        }
    }
    __syncthreads();

    // ---- dk GEMM ----
    #pragma unroll
    for (int kt = 0; kt < 2; ++kt) {
        short8 bf[2][4];
        #pragma unroll
        for (int s = 0; s < 4; ++s) {
            bf[0][s] = *(const short8*)(Wt + (size_t)dj0 * 256 + kt * 128 + s * 32 + lq * 8);
            bf[1][s] = *(const short8*)(Wt + (size_t)dj1 * 256 + kt * 128 + s * 32 + lq * 8);
        }
        #pragma unroll
        for (int i = 0; i < 6; ++i) {
            const int row = i * 16 + l15;
            const int rx  = row & 7;
            #pragma unroll
            for (int s = 0; s < 4; ++s) {
                const int pos = (s * 4 + lq) ^ rx;
                const short8 af = *(const short8*)&As[kt * (96*128) + row * 128 + pos * 8];
                acc[i][0] = __builtin_amdgcn_mfma_f32_16x16x32_bf16(af, bf[0][s], acc[i][0], 0, 0, 0);
                acc[i][1] = __builtin_amdgcn_mfma_f32_16x16x32_bf16(af, bf[1][s], acc[i][1], 0, 0, 0);
            }
        }
    }

    // ---- attention epilogue ----
    float attn0 = 0.f, attn1 = 0.f;
    float t00=0.f, t01=0.f, t02=0.f, t10=0.f, t11=0.f, t12=0.f;

    #pragma unroll
    for (int i = 0; i < 6; ++i) {
        #pragma unroll
        for (int rr = 0; rr < 4; ++rr) {
            const int m = i * 16 + lq * 4 + rr;
            const size_t krow = ((size_t)(b * Nn + m)) << 8;
            const float k0 = kmat[krow + dj0], k1 = kmat[krow + dj1];
            const float v0 = vmat[krow + dj0], v1 = vmat[krow + dj1];
            float pr = silu_f(acc[i][0][rr] + bv0) * k0 * qd0
                     + silu_f(acc[i][1][rr] + bv1) * k1 * qd1;
            #pragma unroll
            for (int off = 8; off; off >>= 1)
                pr += __shfl_xor(pr, off, 16);
            const float p = silu_f(pr) * scl[m];
            const float pv0 = p * v0, pv1 = p * v1;
            attn0 += pv0; attn1 += pv1;
            const float c0 = vcs[m][0], c1 = vcs[m][1], c2 = vcs[m][2];
            t00 = fmaf(c0, pv0, t00); t01 = fmaf(c1, pv0, t01); t02 = fmaf(c2, pv0, t02);
            t10 = fmaf(c0, pv1, t10); t11 = fmaf(c1, pv1, t11); t12 = fmaf(c2, pv1, t12);
        }
    }

    attn0 += __shfl_xor(attn0, 16, 64); attn0 += __shfl_xor(attn0, 32, 64);
    attn1 += __shfl_xor(attn1, 16, 64); attn1 += __shfl_xor(attn1, 32, 64);
    t00 += __shfl_xor(t00, 16, 64); t00 += __shfl_xor(t00, 32, 64);
    t01 += __shfl_xor(t01, 16, 64); t01 += __shfl_xor(t01, 32, 64);
    t02 += __shfl_xor(t02, 16, 64); t02 += __shfl_xor(t02, 32, 64);
    t10 += __shfl_xor(t10, 16, 64); t10 += __shfl_xor(t10, 32, 64);
    t11 += __shfl_xor(t11, 16, 64); t11 += __shfl_xor(t11, 32, 64);
    t12 += __shfl_xor(t12, 16, 64); t12 += __shfl_xor(t12, 32, 64);

    if (lq == 0) {
        attn_out[(size_t)bn * Dd + dj0] = attn0;
        attn_out[(size_t)bn * Dd + dj1] = attn1;
        t_out[((size_t)bn * 3 + 0) * Dd + dj0] = t00;
        t_out[((size_t)bn * 3 + 1) * Dd + dj0] = t01;
        t_out[((size_t)bn * 3 + 2) * Dd + dj0] = t02;
        t_out[((size_t)bn * 3 + 0) * Dd + dj1] = t10;
        t_out[((size_t)bn * 3 + 1) * Dd + dj1] = t11;
        t_out[((size_t)bn * 3 + 2) * Dd + dj1] = t12;
    }
    // wave-parallel sum of vec over unmasked m (3 waves, one per component)
    if (tid < 192) {
        const int c  = tid >> 6;
        const int ln = tid & 63;
        float s = 0.0f;
        for (int m = ln; m < Nn; m += 64)
            if (!mks[m]) s += vcs[m][c];
        #pragma unroll
        for (int off = 32; off; off >>= 1) s += __shfl_xor(s, off, 64);
        if (ln == 0) sv_out[(size_t)bn * 3 + c] = s;
    }

    // ---- ea GEMM: reuse As tiles AND acc registers (zero added pressure) ----
    #pragma unroll
    for (int i = 0; i < 6; ++i) { acc[i][0] = (f32x4){0.f,0.f,0.f,0.f}; acc[i][1] = (f32x4){0.f,0.f,0.f,0.f}; }

    #pragma unroll
    for (int kt = 0; kt < 2; ++kt) {
        short8 bf[2][4];
        #pragma unroll
        for (int s = 0; s < 4; ++s) {
            bf[0][s] = *(const short8*)(Wte + (size_t)dj0 * 256 + kt * 128 + s * 32 + lq * 8);
            bf[1][s] = *(const short8*)(Wte + (size_t)dj1 * 256 + kt * 128 + s * 32 + lq * 8);
        }
        #pragma unroll
        for (int i = 0; i < 6; ++i) {
            const int row = i * 16 + l15;
            const int rx  = row & 7;
            #pragma unroll
            for (int s = 0; s < 4; ++s) {
                const int pos = (s * 4 + lq) ^ rx;
                const short8 af = *(const short8*)&As[kt * (96*128) + row * 128 + pos * 8];
                acc[i][0] = __builtin_amdgcn_mfma_f32_16x16x32_bf16(af, bf[0][s], acc[i][0], 0, 0, 0);
                acc[i][1] = __builtin_amdgcn_mfma_f32_16x16x32_bf16(af, bf[1][s], acc[i][1], 0, 0, 0);
            }
        }
    }

    const float be0 = bea[dj0], be1 = bea[dj1];
    #pragma unroll
    for (int i = 0; i < 6; ++i) {
        #pragma unroll
        for (int rr = 0; rr < 4; ++rr) {
            const int m = i * 16 + lq * 4 + rr;
            const size_t er = ((size_t)bn * Nn + m) * Dd;
            eab[er + dj0] = (unsigned short)f2bf(silu_f(acc[i][0][rr] + be0));
            eab[er + dj1] = (unsigned short)f2bf(silu_f(acc[i][1][rr] + be1));
        }
    }
}

// ---------------- Kernel 3: du = t@Wdu + svec*bdu ; w = du@Wdih -> ws(f32), wt(bf16 packed) ----
__global__ __launch_bounds__(256) void du_kernel(
    const float* __restrict__ t_in, const float* __restrict__ sv_in,
    const float* __restrict__ Wdu, const float* __restrict__ bdu,
    const float* __restrict__ Wdih,
    float* __restrict__ wsv, unsigned short* __restrict__ wtp)
{
    const int bn  = blockIdx.x;
    const int tid = threadIdx.x;
    __shared__ float ts[3][Dd];
    __shared__ float dus[3][Dd];

    #pragma unroll
    for (int j = 0; j < 3; ++j)
        ts[j][tid] = t_in[((size_t)bn * 3 + j) * Dd + tid];
    __syncthreads();

    float du[3];
    const float bd = bdu[tid];
    #pragma unroll
    for (int j = 0; j < 3; ++j) du[j] = sv_in[(size_t)bn * 3 + j] * bd;

    for (int k4 = 0; k4 < 64; ++k4) {
        const float w0 = Wdu[(size_t)(k4 * 4 + 0) * Dd + tid];
        const float w1 = Wdu[(size_t)(k4 * 4 + 1) * Dd + tid];
        const float w2 = Wdu[(size_t)(k4 * 4 + 2) * Dd + tid];
        const float w3 = Wdu[(size_t)(k4 * 4 + 3) * Dd + tid];
        #pragma unroll
        for (int j = 0; j < 3; ++j) {
            const float4 e = *(const float4*)&ts[j][k4 * 4];
            du[j] = fmaf(e.x, w0, fmaf(e.y, w1, fmaf(e.z, w2, fmaf(e.w, w3, du[j]))));
        }
    }
    #pragma unroll
    for (int j = 0; j < 3; ++j) dus[j][tid] = du[j];
    __syncthreads();

    float as[3] = {0.f, 0.f, 0.f}, at[3] = {0.f, 0.f, 0.f};

    for (int k4 = 0; k4 < 64; ++k4) {
        const float s0 = Wdih[(size_t)(k4 * 4 + 0) * 512 + tid];
        const float s1 = Wdih[(size_t)(k4 * 4 + 1) * 512 + tid];
        const float s2 = Wdih[(size_t)(k4 * 4 + 2) * 512 + tid];
        const float s3 = Wdih[(size_t)(k4 * 4 + 3) * 512 + tid];
        const float u0 = Wdih[(size_t)(k4 * 4 + 0) * 512 + 256 + tid];
        const float u1 = Wdih[(size_t)(k4 * 4 + 1) * 512 + 256 + tid];
        const float u2 = Wdih[(size_t)(k4 * 4 + 2) * 512 + 256 + tid];
        const float u3 = Wdih[(size_t)(k4 * 4 + 3) * 512 + 256 + tid];
        #pragma unroll
        for (int j = 0; j < 3; ++j) {
            const float4 e = *(const float4*)&dus[j][k4 * 4];
            as[j] = fmaf(e.x, s0, fmaf(e.y, s1, fmaf(e.z, s2, fmaf(e.w, s3, as[j]))));
            at[j] = fmaf(e.x, u0, fmaf(e.y, u1, fmaf(e.z, u2, fmaf(e.w, u3, at[j]))));
        }
    }
    #pragma unroll
    for (int j = 0; j < 3; ++j)
        wsv[((size_t)bn * 3 + j) * Dd + tid] = as[j];
    ushort4 pk;
    pk.x = (unsigned short)f2bf(at[0]);
    pk.y = (unsigned short)f2bf(at[1]);
    pk.z = (unsigned short)f2bf(at[2]);
    pk.w = 0;
    *(ushort4*)(wtp + ((size_t)bn * Dd + tid) * 4) = pk;
}

// ---------------- Kernel 4: ipe = ea * sum_c ws.wt  (streaming, d-pair vectorized) ----------------
__global__ __launch_bounds__(512) void ipe_kernel(
    const unsigned short* __restrict__ eab,
    const float* __restrict__ wsv, const unsigned short* __restrict__ wtp,
    float* __restrict__ ipe)
{
    const int bid = blockIdx.x;
    const int bn  = (bid & 7) * Nn + (bid >> 3);   // XCD-aware: batch = XCD slot
    const int b   = bid & 7;
    const int tid = threadIdx.x;
    const int d2  = tid & 127;          // d-pair index
    const int mg  = tid >> 7;           // 0..3, 24 m each
    const int d0  = d2 * 2;

    const float w00 = wsv[((size_t)bn * 3 + 0) * Dd + d0];
    const float w01 = wsv[((size_t)bn * 3 + 1) * Dd + d0];
    const float w02 = wsv[((size_t)bn * 3 + 2) * Dd + d0];
    const float w10 = wsv[((size_t)bn * 3 + 0) * Dd + d0 + 1];
    const float w11 = wsv[((size_t)bn * 3 + 1) * Dd + d0 + 1];
    const float w12 = wsv[((size_t)bn * 3 + 2) * Dd + d0 + 1];

    const unsigned short* wrow = wtp + ((size_t)b * Nn * Dd + d0) * 4;
    const unsigned short* erow = eab + (size_t)bn * Nn * Dd + d0;
    float*                orow = ipe + (size_t)bn * Nn * Dd + d0;

    const int m0 = mg * 24;
    #pragma unroll 4
    for (int m = m0; m < m0 + 24; ++m) {
        const short8 w8 = *(const short8*)(wrow + (size_t)m * Dd * 4);
        const unsigned e2 = *(const unsigned*)(erow + (size_t)m * Dd);
        const float e0 = bf2f((unsigned short)(e2 & 0xffffu));
        const float e1 = bf2f((unsigned short)(e2 >> 16));
        float2 o;
        o.x = e0 * (w00 * bf2f((unsigned short)w8[0]) + w01 * bf2f((unsigned short)w8[1])
                  + w02 * bf2f((unsigned short)w8[2]));
        o.y = e1 * (w10 * bf2f((unsigned short)w8[4]) + w11 * bf2f((unsigned short)w8[5])
                  + w12 * bf2f((unsigned short)w8[6]));
        *(float2*)(orow + (size_t)m * Dd) = o;
    }
}

extern "C" void kernel_launch(void* const* d_in, const int* in_sizes, int n_in,
                              void* d_out, int out_size, void* d_ws, size_t ws_size,
                              hipStream_t stream)
{
    const float* x    = (const float*)d_in[0];
    const float* vec  = (const float*)d_in[1];
    const float* dist = (const float*)d_in[2];
    const float* edge = (const float*)d_in[3];
    const int*   mask = (const int*)d_in[4];
    const float* Wq   = (const float*)d_in[5];
    const float* bq   = (const float*)d_in[6];
    const float* Wk   = (const float*)d_in[7];
    const float* bk   = (const float*)d_in[8];
    const float* Wv   = (const float*)d_in[9];
    const float* bv   = (const float*)d_in[10];
    const float* Wdk  = (const float*)d_in[11];
    const float* bdk  = (const float*)d_in[12];
    const float* Wdu  = (const float*)d_in[13];
    const float* bdu  = (const float*)d_in[14];
    const float* Wdih = (const float*)d_in[15];
    const float* Wea  = (const float*)d_in[16];
    const float* bea  = (const float*)d_in[17];

    float* out_attn = (float*)d_out;
    float* out_ipe  = out_attn + (size_t)BN * Dd;

    char* wsp = (char*)d_ws;
    unsigned short* ebf  = (unsigned short*)wsp;  wsp += (size_t)MT * Dd * 2;
    unsigned short* eab  = (unsigned short*)wsp;  wsp += (size_t)MT * Dd * 2;
    float* qb   = (float*)wsp;                    wsp += (size_t)BN * Dd * 4;
    float* kb   = (float*)wsp;                    wsp += (size_t)BN * Dd * 4;
    float* vb   = (float*)wsp;                    wsp += (size_t)BN * Dd * 4;
    float* tb   = (float*)wsp;                    wsp += (size_t)BN * 3 * Dd * 4;
    float* svb  = (float*)wsp;                    wsp += (size_t)BN * 4 * 4;
    float* wsvp = (float*)wsp;                    wsp += (size_t)BN * 3 * Dd * 4;
    unsigned short* wtpp = (unsigned short*)wsp;  wsp += (size_t)BN * Dd * 4 * 2;
    short* Wtdk = (short*)wsp;                    wsp += (size_t)Dd * Dd * 2;
    short* Wtea = (short*)wsp;                    wsp += (size_t)Dd * Dd * 2;

    setup_kernel<<<QKV_BLOCKS + WT_BLOCKS + PREP_BLOCKS, 256, 0, stream>>>(
        edge, ebf, Wdk, Wea, Wtdk, Wtea,
        x, Wq, bq, Wk, bk, Wv, bv, qb, kb, vb);
    dk_attn_kernel<<<BN, 512, 0, stream>>>(ebf, Wtdk, Wtea, bdk, bea,
                                           qb, kb, vb, mask, dist, vec,
                                           out_attn, tb, svb, eab);
    du_kernel<<<BN, 256, 0, stream>>>(tb, svb, Wdu, bdu, Wdih, wsvp, wtpp);
    ipe_kernel<<<BN, 512, 0, stream>>>(eab, wsvp, wtpp, out_ipe);
}

// Round 10
// 265.738 us; speedup vs baseline: 1.1063x; 1.1063x over previous
//
#include <hip/hip_runtime.h>
#include <hip/hip_bf16.h>
#include <math.h>

#define Bb 8
#define Nn 96
#define Dd 256
#define BN (Bb*Nn)      /* 768 */
#define MT (BN*Nn)      /* 73728 edge rows */
#define PI_OVER_CUTOFF 0.62831853071795864769f  /* pi/5 */

#define QKV_ROWS    8
#define QKV_BLOCKS  ((BN / QKV_ROWS) * 3)  /* 288, dispatched FIRST (latency-chained) */
#define WT_BLOCKS   512
#define PREP_BLOCKS (MT * Dd / (256*16))   /* 4608: 16 elts/thread streaming */

typedef short short8 __attribute__((ext_vector_type(8)));
typedef float f32x4  __attribute__((ext_vector_type(4)));

// fast silu: v_exp_f32 + v_rcp_f32 are ~1ulp; inputs already bf16-quantized.
__device__ __forceinline__ float silu_f(float x){
    return x * __builtin_amdgcn_rcpf(1.0f + __expf(-x));
}

__device__ __forceinline__ short f2bf(float f){
    __hip_bfloat16 h = __float2bfloat16(f);
    return __builtin_bit_cast(short, h);
}
__device__ __forceinline__ float bf2f(unsigned short u){
    union { unsigned uu; float ff; } a; a.uu = ((unsigned)u) << 16; return a.ff;
}

// async global->LDS, 16B per lane. LDS dest = base + lane*16 (wave-uniform base).
__device__ __forceinline__ void gll16(short* lds, const unsigned short* g){
    __builtin_amdgcn_global_load_lds(
        (const __attribute__((address_space(1))) unsigned int*)g,
        (__attribute__((address_space(3))) unsigned int*)lds, 16, 0, 0);
}

// ---------------- Kernel 1: setup = qkv (8-row GEMV, first) + wt + prep (stream) ----------------
__global__ __launch_bounds__(256) void setup_kernel(
    const float* __restrict__ edge, unsigned short* __restrict__ ebf,
    const float* __restrict__ Wdk, const float* __restrict__ Wea,
    short* __restrict__ Wtdk, short* __restrict__ Wtea,
    const float* __restrict__ x,
    const float* __restrict__ Wq, const float* __restrict__ bq,
    const float* __restrict__ Wk, const float* __restrict__ bk,
    const float* __restrict__ Wv, const float* __restrict__ bv,
    float* __restrict__ qo, float* __restrict__ ko, float* __restrict__ vo)
{
    const int blk = blockIdx.x;
    const int tid = threadIdx.x;

    if (blk < QKV_BLOCKS) {
        // ---- qkv: 8 rows/block. 4 W loads feed 32 FMAs (8 indep chains) per iter. ----
        __shared__ float xs[QKV_ROWS][Dd];
        const int idx = blk;
        const int sel = idx % 3;
        const int r0  = (idx / 3) * QKV_ROWS;
        const float* W  = sel == 0 ? Wq : (sel == 1 ? Wk : Wv);
        const float* bb = sel == 0 ? bq : (sel == 1 ? bk : bv);
        float*       ou = sel == 0 ? qo : (sel == 1 ? ko : vo);

        #pragma unroll
        for (int i = 0; i < QKV_ROWS; ++i) xs[i][tid] = x[(size_t)(r0 + i) * Dd + tid];
        __syncthreads();

        float a[QKV_ROWS];
        const float bvv = bb[tid];
        #pragma unroll
        for (int i = 0; i < QKV_ROWS; ++i) a[i] = bvv;

        for (int k4 = 0; k4 < 64; ++k4) {
            const float w0 = W[(size_t)(k4 * 4 + 0) * Dd + tid];
            const float w1 = W[(size_t)(k4 * 4 + 1) * Dd + tid];
            const float w2 = W[(size_t)(k4 * 4 + 2) * Dd + tid];
            const float w3 = W[(size_t)(k4 * 4 + 3) * Dd + tid];
            #pragma unroll
            for (int i = 0; i < QKV_ROWS; ++i) {
                const float4 e = *(const float4*)&xs[i][k4 * 4];
                a[i] = fmaf(e.x, w0, fmaf(e.y, w1, fmaf(e.z, w2, fmaf(e.w, w3, a[i]))));
            }
        }
        #pragma unroll
        for (int i = 0; i < QKV_ROWS; ++i)
            ou[(size_t)(r0 + i) * Dd + tid] = a[i];
        return;
    }
    if (blk < QKV_BLOCKS + WT_BLOCKS) {
        // ---- Wt = bf16(W^T): coalesced READ, scattered 2B write (fire-and-forget) ----
        const int o   = (blk - QKV_BLOCKS) * 256 + tid;
        const int sel = o >> 16;
        const int r   = o & 65535;           // r = k*256 + n (source-linear)
        const float* src = sel ? Wea : Wdk;
        short*       dst = sel ? Wtea : Wtdk;
        dst[(r & 255) * 256 + (r >> 8)] = f2bf(src[r]);
        return;
    }

    // ---- prep: edge fp32 -> bf16, 16 elts/thread (4 independent float4 loads).
    //      Plain cacheable loads: edge is L3-resident after harness poison; nt reads
    //      bypassed L3 and cost ~4us in R7's A/B. ----
    const size_t idx = ((size_t)(blk - QKV_BLOCKS - WT_BLOCKS) * 256 + tid) * 16;
    const f32x4 a = *(const f32x4*)(edge + idx);
    const f32x4 b = *(const f32x4*)(edge + idx + 4);
    const f32x4 c = *(const f32x4*)(edge + idx + 8);
    const f32x4 d = *(const f32x4*)(edge + idx + 12);
    short8 s0, s1;
    s0[0]=f2bf(a[0]); s0[1]=f2bf(a[1]); s0[2]=f2bf(a[2]); s0[3]=f2bf(a[3]);
    s0[4]=f2bf(b[0]); s0[5]=f2bf(b[1]); s0[6]=f2bf(b[2]); s0[7]=f2bf(b[3]);
    s1[0]=f2bf(c[0]); s1[1]=f2bf(c[1]); s1[2]=f2bf(c[2]); s1[3]=f2bf(c[3]);
    s1[4]=f2bf(d[0]); s1[5]=f2bf(d[1]); s1[6]=f2bf(d[2]); s1[7]=f2bf(d[3]);
    *(short8*)(ebf + idx)     = s0;
    *(short8*)(ebf + idx + 8) = s1;
}

// ---------------- Kernel 2: fused dk-GEMM (MFMA, async staged) + attention ----------------
// 512 thr = 8 waves; wave w owns cols [w*32,+32) = head w. 96 rows (m), K=256 staged
// in one shot (both 128-chunks in LDS via global_load_lds, single barrier).
__global__ __launch_bounds__(512, 4) void dk_attn_kernel(
    const unsigned short* __restrict__ ebf, const short* __restrict__ Wt,
    const float* __restrict__ bdk,
    const float* __restrict__ q, const float* __restrict__ kmat, const float* __restrict__ vmat,
    const int* __restrict__ mask, const float* __restrict__ dist, const float* __restrict__ vec,
    float* __restrict__ attn_out, float* __restrict__ t_out, float* __restrict__ sv_out)
{
    __shared__ short As[2 * 96 * 128];   // 48 KB, both K-chunks resident
    __shared__ float scl[Nn];
    __shared__ float vcs[Nn][3];
    __shared__ int   mks[Nn];

    const int bn   = blockIdx.x;
    const int b    = bn / Nn;
    const int tid  = threadIdx.x;
    const int lane = tid & 63;
    const int w    = tid >> 6;
    const int l15  = lane & 15;
    const int lq   = lane >> 4;

    if (tid < Nn) {
        const int   mm = mask[(size_t)bn * Nn + tid];
        const float di = dist[(size_t)bn * Nn + tid];
        const float s  = (di < 5.0f) ? 0.5f * (__cosf(di * PI_OVER_CUTOFF) + 1.0f) : 0.0f;
        scl[tid] = mm ? 0.0f : s;
        mks[tid] = mm;
    }
    for (int j = tid; j < Nn * 3; j += 512)
        (&vcs[0][0])[j] = vec[(size_t)bn * Nn * 3 + j];

    const int dj0 = w * 32 + l15, dj1 = dj0 + 16;
    const float qd0 = q[(size_t)bn * Dd + dj0], qd1 = q[(size_t)bn * Dd + dj1];
    const float bv0 = bdk[dj0], bv1 = bdk[dj1];

    f32x4 acc[6][2];
    #pragma unroll
    for (int i = 0; i < 6; ++i) { acc[i][0] = (f32x4){0.f,0.f,0.f,0.f}; acc[i][1] = (f32x4){0.f,0.f,0.f,0.f}; }

    const unsigned short* ebase = ebf + (size_t)bn * Nn * Dd;
    const int srow = (lane >> 4);          // 0..3 within chunk
    const int cs   = lane & 15;            // stored segment

    // stage BOTH K-chunks, then one barrier
    #pragma unroll
    for (int kt = 0; kt < 2; ++kt) {
        #pragma unroll
        for (int u = 0; u < 3; ++u) {
            const int chunk = w * 3 + u;           // 0..23, 4 rows each
            const int r     = chunk * 4 + srow;
            const int gseg  = cs ^ (r & 7);
            gll16(As + kt * (96*128) + chunk * 512,
                  ebase + (size_t)r * Dd + kt * 128 + gseg * 8);
        }
    }
    __syncthreads();

    #pragma unroll
    for (int kt = 0; kt < 2; ++kt) {
        short8 bf[2][4];
        #pragma unroll
        for (int s = 0; s < 4; ++s) {
            bf[0][s] = *(const short8*)(Wt + (size_t)dj0 * 256 + kt * 128 + s * 32 + lq * 8);
            bf[1][s] = *(const short8*)(Wt + (size_t)dj1 * 256 + kt * 128 + s * 32 + lq * 8);
        }
        #pragma unroll
        for (int i = 0; i < 6; ++i) {
            const int row = i * 16 + l15;
            const int rx  = row & 7;
            #pragma unroll
            for (int s = 0; s < 4; ++s) {
                const int pos = (s * 4 + lq) ^ rx;
                const short8 af = *(const short8*)&As[kt * (96*128) + row * 128 + pos * 8];
                acc[i][0] = __builtin_amdgcn_mfma_f32_16x16x32_bf16(af, bf[0][s], acc[i][0], 0, 0, 0);
                acc[i][1] = __builtin_amdgcn_mfma_f32_16x16x32_bf16(af, bf[1][s], acc[i][1], 0, 0, 0);
            }
        }
    }

    float attn0 = 0.f, attn1 = 0.f;
    float t00=0.f, t01=0.f, t02=0.f, t10=0.f, t11=0.f, t12=0.f;

    #pragma unroll
    for (int i = 0; i < 6; ++i) {
        #pragma unroll
        for (int rr = 0; rr < 4; ++rr) {
            const int m = i * 16 + lq * 4 + rr;
            const size_t krow = ((size_t)(b * Nn + m)) << 8;
            const float k0 = kmat[krow + dj0], k1 = kmat[krow + dj1];
            const float v0 = vmat[krow + dj0], v1 = vmat[krow + dj1];
            float pr = silu_f(acc[i][0][rr] + bv0) * k0 * qd0
                     + silu_f(acc[i][1][rr] + bv1) * k1 * qd1;
            #pragma unroll
            for (int off = 8; off; off >>= 1)
                pr += __shfl_xor(pr, off, 16);
            const float p = silu_f(pr) * scl[m];
            const float pv0 = p * v0, pv1 = p * v1;
            attn0 += pv0; attn1 += pv1;
            const float c0 = vcs[m][0], c1 = vcs[m][1], c2 = vcs[m][2];
            t00 = fmaf(c0, pv0, t00); t01 = fmaf(c1, pv0, t01); t02 = fmaf(c2, pv0, t02);
            t10 = fmaf(c0, pv1, t10); t11 = fmaf(c1, pv1, t11); t12 = fmaf(c2, pv1, t12);
        }
    }

    attn0 += __shfl_xor(attn0, 16, 64); attn0 += __shfl_xor(attn0, 32, 64);
    attn1 += __shfl_xor(attn1, 16, 64); attn1 += __shfl_xor(attn1, 32, 64);
    t00 += __shfl_xor(t00, 16, 64); t00 += __shfl_xor(t00, 32, 64);
    t01 += __shfl_xor(t01, 16, 64); t01 += __shfl_xor(t01, 32, 64);
    t02 += __shfl_xor(t02, 16, 64); t02 += __shfl_xor(t02, 32, 64);
    t10 += __shfl_xor(t10, 16, 64); t10 += __shfl_xor(t10, 32, 64);
    t11 += __shfl_xor(t11, 16, 64); t11 += __shfl_xor(t11, 32, 64);
    t12 += __shfl_xor(t12, 16, 64); t12 += __shfl_xor(t12, 32, 64);

    if (lq == 0) {
        attn_out[(size_t)bn * Dd + dj0] = attn0;
        attn_out[(size_t)bn * Dd + dj1] = attn1;
        t_out[((size_t)bn * 3 + 0) * Dd + dj0] = t00;
        t_out[((size_t)bn * 3 + 1) * Dd + dj0] = t01;
        t_out[((size_t)bn * 3 + 2) * Dd + dj0] = t02;
        t_out[((size_t)bn * 3 + 0) * Dd + dj1] = t10;
        t_out[((size_t)bn * 3 + 1) * Dd + dj1] = t11;
        t_out[((size_t)bn * 3 + 2) * Dd + dj1] = t12;
    }
    // wave-parallel sum of vec over unmasked m (3 waves, one per component)
    if (tid < 192) {
        const int c  = tid >> 6;
        const int ln = tid & 63;
        float s = 0.0f;
        for (int m = ln; m < Nn; m += 64)
            if (!mks[m]) s += vcs[m][c];
        #pragma unroll
        for (int off = 32; off; off >>= 1) s += __shfl_xor(s, off, 64);
        if (ln == 0) sv_out[(size_t)bn * 3 + c] = s;
    }
}

// ---------------- Kernel 3: du = t@Wdu + svec*bdu ; w = du@Wdih -> ws(f32), wt(bf16 packed) ----
__global__ __launch_bounds__(256) void du_kernel(
    const float* __restrict__ t_in, const float* __restrict__ sv_in,
    const float* __restrict__ Wdu, const float* __restrict__ bdu,
    const float* __restrict__ Wdih,
    float* __restrict__ wsv, unsigned short* __restrict__ wtp)
{
    const int bn  = blockIdx.x;
    const int tid = threadIdx.x;
    __shared__ float ts[3][Dd];
    __shared__ float dus[3][Dd];

    #pragma unroll
    for (int j = 0; j < 3; ++j)
        ts[j][tid] = t_in[((size_t)bn * 3 + j) * Dd + tid];
    __syncthreads();

    float du[3];
    const float bd = bdu[tid];
    #pragma unroll
    for (int j = 0; j < 3; ++j) du[j] = sv_in[(size_t)bn * 3 + j] * bd;

    for (int k4 = 0; k4 < 64; ++k4) {
        const float w0 = Wdu[(size_t)(k4 * 4 + 0) * Dd + tid];
        const float w1 = Wdu[(size_t)(k4 * 4 + 1) * Dd + tid];
        const float w2 = Wdu[(size_t)(k4 * 4 + 2) * Dd + tid];
        const float w3 = Wdu[(size_t)(k4 * 4 + 3) * Dd + tid];
        #pragma unroll
        for (int j = 0; j < 3; ++j) {
            const float4 e = *(const float4*)&ts[j][k4 * 4];
            du[j] = fmaf(e.x, w0, fmaf(e.y, w1, fmaf(e.z, w2, fmaf(e.w, w3, du[j]))));
        }
    }
    #pragma unroll
    for (int j = 0; j < 3; ++j) dus[j][tid] = du[j];
    __syncthreads();

    float as[3] = {0.f, 0.f, 0.f}, at[3] = {0.f, 0.f, 0.f};

    for (int k4 = 0; k4 < 64; ++k4) {
        const float s0 = Wdih[(size_t)(k4 * 4 + 0) * 512 + tid];
        const float s1 = Wdih[(size_t)(k4 * 4 + 1) * 512 + tid];
        const float s2 = Wdih[(size_t)(k4 * 4 + 2) * 512 + tid];
        const float s3 = Wdih[(size_t)(k4 * 4 + 3) * 512 + tid];
        const float u0 = Wdih[(size_t)(k4 * 4 + 0) * 512 + 256 + tid];
        const float u1 = Wdih[(size_t)(k4 * 4 + 1) * 512 + 256 + tid];
        const float u2 = Wdih[(size_t)(k4 * 4 + 2) * 512 + 256 + tid];
        const float u3 = Wdih[(size_t)(k4 * 4 + 3) * 512 + 256 + tid];
        #pragma unroll
        for (int j = 0; j < 3; ++j) {
            const float4 e = *(const float4*)&dus[j][k4 * 4];
            as[j] = fmaf(e.x, s0, fmaf(e.y, s1, fmaf(e.z, s2, fmaf(e.w, s3, as[j]))));
            at[j] = fmaf(e.x, u0, fmaf(e.y, u1, fmaf(e.z, u2, fmaf(e.w, u3, at[j]))));
        }
    }
    #pragma unroll
    for (int j = 0; j < 3; ++j)
        wsv[((size_t)bn * 3 + j) * Dd + tid] = as[j];
    ushort4 pk;
    pk.x = (unsigned short)f2bf(at[0]);
    pk.y = (unsigned short)f2bf(at[1]);
    pk.z = (unsigned short)f2bf(at[2]);
    pk.w = 0;
    *(ushort4*)(wtp + ((size_t)bn * Dd + tid) * 4) = pk;
}

// ---------------- Kernel 4: ipe = silu(edge@Wea + bea) * sum_c ws.wt (async-staged MFMA) ----------------
__global__ __launch_bounds__(512, 4) void ea_ipe_kernel(
    const unsigned short* __restrict__ ebf, const short* __restrict__ Wt,
    const float* __restrict__ bea,
    const float* __restrict__ wsv, const unsigned short* __restrict__ wtp,
    float* __restrict__ ipe)
{
    __shared__ short As[2 * 96 * 128];
    const int bn   = blockIdx.x;
    const int b    = bn / Nn;
    const int tid  = threadIdx.x;
    const int lane = tid & 63;
    const int w    = tid >> 6;
    const int l15  = lane & 15;
    const int lq   = lane >> 4;

    const int dj0 = w * 32 + l15, dj1 = dj0 + 16;
    const float be0 = bea[dj0], be1 = bea[dj1];
    const float ws00 = wsv[((size_t)bn*3+0)*Dd + dj0], ws01 = wsv[((size_t)bn*3+1)*Dd + dj0],
                ws02 = wsv[((size_t)bn*3+2)*Dd + dj0];
    const float ws10 = wsv[((size_t)bn*3+0)*Dd + dj1], ws11 = wsv[((size_t)bn*3+1)*Dd + dj1],
                ws12 = wsv[((size_t)bn*3+2)*Dd + dj1];

    f32x4 acc[6][2];
    #pragma unroll
    for (int i = 0; i < 6; ++i) { acc[i][0] = (f32x4){0.f,0.f,0.f,0.f}; acc[i][1] = (f32x4){0.f,0.f,0.f,0.f}; }

    const unsigned short* ebase = ebf + (size_t)bn * Nn * Dd;
    const int srow = (lane >> 4);
    const int cs   = lane & 15;

    #pragma unroll
    for (int kt = 0; kt < 2; ++kt) {
        #pragma unroll
        for (int u = 0; u < 3; ++u) {
            const int chunk = w * 3 + u;
            const int r     = chunk * 4 + srow;
            const int gseg  = cs ^ (r & 7);
            gll16(As + kt * (96*128) + chunk * 512,
                  ebase + (size_t)r * Dd + kt * 128 + gseg * 8);
        }
    }
    __syncthreads();

    #pragma unroll
    for (int kt = 0; kt < 2; ++kt) {
        short8 bf[2][4];
        #pragma unroll
        for (int s = 0; s < 4; ++s) {
            bf[0][s] = *(const short8*)(Wt + (size_t)dj0 * 256 + kt * 128 + s * 32 + lq * 8);
            bf[1][s] = *(const short8*)(Wt + (size_t)dj1 * 256 + kt * 128 + s * 32 + lq * 8);
        }
        #pragma unroll
        for (int i = 0; i < 6; ++i) {
            const int row = i * 16 + l15;
            const int rx  = row & 7;
            #pragma unroll
            for (int s = 0; s < 4; ++s) {
                const int pos = (s * 4 + lq) ^ rx;
                const short8 af = *(const short8*)&As[kt * (96*128) + row * 128 + pos * 8];
                acc[i][0] = __builtin_amdgcn_mfma_f32_16x16x32_bf16(af, bf[0][s], acc[i][0], 0, 0, 0);
                acc[i][1] = __builtin_amdgcn_mfma_f32_16x16x32_bf16(af, bf[1][s], acc[i][1], 0, 0, 0);
            }
        }
    }

    #pragma unroll
    for (int i = 0; i < 6; ++i) {
        #pragma unroll
        for (int rr = 0; rr < 4; ++rr) {
            const int m = i * 16 + lq * 4 + rr;
            const size_t wr = (size_t)(b * Nn + m);
            const ushort4 w40 = *(const ushort4*)(wtp + (wr * Dd + dj0) * 4);
            const ushort4 w41 = *(const ushort4*)(wtp + (wr * Dd + dj1) * 4);
            const float ea0 = silu_f(acc[i][0][rr] + be0);
            const float ea1 = silu_f(acc[i][1][rr] + be1);
            const float sd0 = ws00 * bf2f(w40.x) + ws01 * bf2f(w40.y) + ws02 * bf2f(w40.z);
            const float sd1 = ws10 * bf2f(w41.x) + ws11 * bf2f(w41.y) + ws12 * bf2f(w41.z);
            ipe[((size_t)bn * Nn + m) * Dd + dj0] = ea0 * sd0;
            ipe[((size_t)bn * Nn + m) * Dd + dj1] = ea1 * sd1;
        }
    }
}

extern "C" void kernel_launch(void* const* d_in, const int* in_sizes, int n_in,
                              void* d_out, int out_size, void* d_ws, size_t ws_size,
                              hipStream_t stream)
{
    const float* x    = (const float*)d_in[0];
    const float* vec  = (const float*)d_in[1];
    const float* dist = (const float*)d_in[2];
    const float* edge = (const float*)d_in[3];
    const int*   mask = (const int*)d_in[4];
    const float* Wq   = (const float*)d_in[5];
    const float* bq   = (const float*)d_in[6];
    const float* Wk   = (const float*)d_in[7];
    const float* bk   = (const float*)d_in[8];
    const float* Wv   = (const float*)d_in[9];
    const float* bv   = (const float*)d_in[10];
    const float* Wdk  = (const float*)d_in[11];
    const float* bdk  = (const float*)d_in[12];
    const float* Wdu  = (const float*)d_in[13];
    const float* bdu  = (const float*)d_in[14];
    const float* Wdih = (const float*)d_in[15];
    const float* Wea  = (const float*)d_in[16];
    const float* bea  = (const float*)d_in[17];

    float* out_attn = (float*)d_out;
    float* out_ipe  = out_attn + (size_t)BN * Dd;

    char* wsp = (char*)d_ws;
    unsigned short* ebf  = (unsigned short*)wsp;  wsp += (size_t)MT * Dd * 2;
    float* qb   = (float*)wsp;                    wsp += (size_t)BN * Dd * 4;
    float* kb   = (float*)wsp;                    wsp += (size_t)BN * Dd * 4;
    float* vb   = (float*)wsp;                    wsp += (size_t)BN * Dd * 4;
    float* tb   = (float*)wsp;                    wsp += (size_t)BN * 3 * Dd * 4;
    float* svb  = (float*)wsp;                    wsp += (size_t)BN * 4 * 4;
    float* wsvp = (float*)wsp;                    wsp += (size_t)BN * 3 * Dd * 4;
    unsigned short* wtpp = (unsigned short*)wsp;  wsp += (size_t)BN * Dd * 4 * 2;
    short* Wtdk = (short*)wsp;                    wsp += (size_t)Dd * Dd * 2;
    short* Wtea = (short*)wsp;                    wsp += (size_t)Dd * Dd * 2;

    setup_kernel<<<QKV_BLOCKS + WT_BLOCKS + PREP_BLOCKS, 256, 0, stream>>>(
        edge, ebf, Wdk, Wea, Wtdk, Wtea,
        x, Wq, bq, Wk, bk, Wv, bv, qb, kb, vb);
    dk_attn_kernel<<<BN, 512, 0, stream>>>(ebf, Wtdk, bdk, qb, kb, vb, mask, dist, vec,
                                           out_attn, tb, svb);
    du_kernel<<<BN, 256, 0, stream>>>(tb, svb, Wdu, bdu, Wdih, wsvp, wtpp);
    ea_ipe_kernel<<<BN, 512, 0, stream>>>(ebf, Wtea, bea, wsvp, wtpp, out_ipe);
}

// Round 11
// 264.091 us; speedup vs baseline: 1.1132x; 1.0062x over previous
//
#include <hip/hip_runtime.h>
#include <hip/hip_bf16.h>
#include <math.h>

#define Bb 8
#define Nn 96
#define Dd 256
#define BN (Bb*Nn)      /* 768 */
#define MT (BN*Nn)      /* 73728 edge rows */
#define PI_OVER_CUTOFF 0.62831853071795864769f  /* pi/5 */

#define QKV_ROWS    8
#define QKV_BLOCKS  ((BN / QKV_ROWS) * 3)  /* 288, dispatched FIRST (latency-chained) */
#define WT_BLOCKS   512
#define PREP_BLOCKS (MT * Dd / (256*16))   /* 4608: 16 elts/thread streaming */

typedef short short8 __attribute__((ext_vector_type(8)));
typedef float f32x4  __attribute__((ext_vector_type(4)));

// fast silu: v_exp_f32 + v_rcp_f32 are ~1ulp; inputs already bf16-quantized.
__device__ __forceinline__ float silu_f(float x){
    return x * __builtin_amdgcn_rcpf(1.0f + __expf(-x));
}

__device__ __forceinline__ short f2bf(float f){
    __hip_bfloat16 h = __float2bfloat16(f);
    return __builtin_bit_cast(short, h);
}
__device__ __forceinline__ float bf2f(unsigned short u){
    union { unsigned uu; float ff; } a; a.uu = ((unsigned)u) << 16; return a.ff;
}

// async global->LDS, 16B per lane. LDS dest = base + lane*16 (wave-uniform base).
__device__ __forceinline__ void gll16(short* lds, const unsigned short* g){
    __builtin_amdgcn_global_load_lds(
        (const __attribute__((address_space(1))) unsigned int*)g,
        (__attribute__((address_space(3))) unsigned int*)lds, 16, 0, 0);
}

// ---------------- Kernel 1: setup = qkv (8-row GEMV, first) + wt + prep (stream) ----------------
__global__ __launch_bounds__(256) void setup_kernel(
    const float* __restrict__ edge, unsigned short* __restrict__ ebf,
    const float* __restrict__ Wdk, const float* __restrict__ Wea,
    short* __restrict__ Wtdk, short* __restrict__ Wtea,
    const float* __restrict__ x,
    const float* __restrict__ Wq, const float* __restrict__ bq,
    const float* __restrict__ Wk, const float* __restrict__ bk,
    const float* __restrict__ Wv, const float* __restrict__ bv,
    float* __restrict__ qo, float* __restrict__ ko, float* __restrict__ vo)
{
    const int blk = blockIdx.x;
    const int tid = threadIdx.x;

    if (blk < QKV_BLOCKS) {
        // ---- qkv: 8 rows/block. 4 W loads feed 32 FMAs (8 indep chains) per iter. ----
        __shared__ float xs[QKV_ROWS][Dd];
        const int idx = blk;
        const int sel = idx % 3;
        const int r0  = (idx / 3) * QKV_ROWS;
        const float* W  = sel == 0 ? Wq : (sel == 1 ? Wk : Wv);
        const float* bb = sel == 0 ? bq : (sel == 1 ? bk : bv);
        float*       ou = sel == 0 ? qo : (sel == 1 ? ko : vo);

        #pragma unroll
        for (int i = 0; i < QKV_ROWS; ++i) xs[i][tid] = x[(size_t)(r0 + i) * Dd + tid];
        __syncthreads();

        float a[QKV_ROWS];
        const float bvv = bb[tid];
        #pragma unroll
        for (int i = 0; i < QKV_ROWS; ++i) a[i] = bvv;

        for (int k4 = 0; k4 < 64; ++k4) {
            const float w0 = W[(size_t)(k4 * 4 + 0) * Dd + tid];
            const float w1 = W[(size_t)(k4 * 4 + 1) * Dd + tid];
            const float w2 = W[(size_t)(k4 * 4 + 2) * Dd + tid];
            const float w3 = W[(size_t)(k4 * 4 + 3) * Dd + tid];
            #pragma unroll
            for (int i = 0; i < QKV_ROWS; ++i) {
                const float4 e = *(const float4*)&xs[i][k4 * 4];
                a[i] = fmaf(e.x, w0, fmaf(e.y, w1, fmaf(e.z, w2, fmaf(e.w, w3, a[i]))));
            }
        }
        #pragma unroll
        for (int i = 0; i < QKV_ROWS; ++i)
            ou[(size_t)(r0 + i) * Dd + tid] = a[i];
        return;
    }
    if (blk < QKV_BLOCKS + WT_BLOCKS) {
        // ---- Wt = bf16(W^T): coalesced READ, scattered 2B write (fire-and-forget) ----
        const int o   = (blk - QKV_BLOCKS) * 256 + tid;
        const int sel = o >> 16;
        const int r   = o & 65535;           // r = k*256 + n (source-linear)
        const float* src = sel ? Wea : Wdk;
        short*       dst = sel ? Wtea : Wtdk;
        dst[(r & 255) * 256 + (r >> 8)] = f2bf(src[r]);
        return;
    }

    // ---- prep: edge fp32 -> bf16, 16 elts/thread (4 independent float4 loads) ----
    const size_t idx = ((size_t)(blk - QKV_BLOCKS - WT_BLOCKS) * 256 + tid) * 16;
    const f32x4 a = *(const f32x4*)(edge + idx);
    const f32x4 b = *(const f32x4*)(edge + idx + 4);
    const f32x4 c = *(const f32x4*)(edge + idx + 8);
    const f32x4 d = *(const f32x4*)(edge + idx + 12);
    short8 s0, s1;
    s0[0]=f2bf(a[0]); s0[1]=f2bf(a[1]); s0[2]=f2bf(a[2]); s0[3]=f2bf(a[3]);
    s0[4]=f2bf(b[0]); s0[5]=f2bf(b[1]); s0[6]=f2bf(b[2]); s0[7]=f2bf(b[3]);
    s1[0]=f2bf(c[0]); s1[1]=f2bf(c[1]); s1[2]=f2bf(c[2]); s1[3]=f2bf(c[3]);
    s1[4]=f2bf(d[0]); s1[5]=f2bf(d[1]); s1[6]=f2bf(d[2]); s1[7]=f2bf(d[3]);
    *(short8*)(ebf + idx)     = s0;
    *(short8*)(ebf + idx + 8) = s1;
}

// ---------------- Kernel 2: fused dk-GEMM + attention + du (As reused as scratch) ----------------
// 512 thr = 8 waves; wave w owns cols [w*32,+32) = head w. 96 rows (m), K=256 staged
// once via global_load_lds, single barrier. After the attn epilogue the dead As buffer
// becomes LDS scratch for the du GEMVs (t never leaves the block): split-k across all
// 512 threads (2 halves x 32 k4-iters + LDS combine) -> wsv (f32) + wtp (bf16 packed).
__global__ __launch_bounds__(512, 4) void dk_attn_kernel(
    const unsigned short* __restrict__ ebf, const short* __restrict__ Wt,
    const float* __restrict__ bdk,
    const float* __restrict__ q, const float* __restrict__ kmat, const float* __restrict__ vmat,
    const int* __restrict__ mask, const float* __restrict__ dist, const float* __restrict__ vec,
    const float* __restrict__ Wdu, const float* __restrict__ bdu,
    const float* __restrict__ Wdih,
    float* __restrict__ attn_out,
    float* __restrict__ wsv, unsigned short* __restrict__ wtp)
{
    __shared__ short As[2 * 96 * 128];   // 48 KB; GEMM tiles, then du scratch
    __shared__ float scl[Nn];
    __shared__ float vcs[Nn][3];
    __shared__ int   mks[Nn];
    __shared__ float svs[4];

    const int bn   = blockIdx.x;
    const int b    = bn / Nn;
    const int tid  = threadIdx.x;
    const int lane = tid & 63;
    const int w    = tid >> 6;
    const int l15  = lane & 15;
    const int lq   = lane >> 4;

    if (tid < Nn) {
        const int   mm = mask[(size_t)bn * Nn + tid];
        const float di = dist[(size_t)bn * Nn + tid];
        const float s  = (di < 5.0f) ? 0.5f * (__cosf(di * PI_OVER_CUTOFF) + 1.0f) : 0.0f;
        scl[tid] = mm ? 0.0f : s;
        mks[tid] = mm;
    }
    for (int j = tid; j < Nn * 3; j += 512)
        (&vcs[0][0])[j] = vec[(size_t)bn * Nn * 3 + j];

    const int dj0 = w * 32 + l15, dj1 = dj0 + 16;
    const float qd0 = q[(size_t)bn * Dd + dj0], qd1 = q[(size_t)bn * Dd + dj1];
    const float bv0 = bdk[dj0], bv1 = bdk[dj1];

    f32x4 acc[6][2];
    #pragma unroll
    for (int i = 0; i < 6; ++i) { acc[i][0] = (f32x4){0.f,0.f,0.f,0.f}; acc[i][1] = (f32x4){0.f,0.f,0.f,0.f}; }

    const unsigned short* ebase = ebf + (size_t)bn * Nn * Dd;
    const int srow = (lane >> 4);          // 0..3 within chunk
    const int cs   = lane & 15;            // stored segment

    // stage BOTH K-chunks, then one barrier
    #pragma unroll
    for (int kt = 0; kt < 2; ++kt) {
        #pragma unroll
        for (int u = 0; u < 3; ++u) {
            const int chunk = w * 3 + u;           // 0..23, 4 rows each
            const int r     = chunk * 4 + srow;
            const int gseg  = cs ^ (r & 7);
            gll16(As + kt * (96*128) + chunk * 512,
                  ebase + (size_t)r * Dd + kt * 128 + gseg * 8);
        }
    }
    __syncthreads();

    #pragma unroll
    for (int kt = 0; kt < 2; ++kt) {
        short8 bf[2][4];
        #pragma unroll
        for (int s = 0; s < 4; ++s) {
            bf[0][s] = *(const short8*)(Wt + (size_t)dj0 * 256 + kt * 128 + s * 32 + lq * 8);
            bf[1][s] = *(const short8*)(Wt + (size_t)dj1 * 256 + kt * 128 + s * 32 + lq * 8);
        }
        #pragma unroll
        for (int i = 0; i < 6; ++i) {
            const int row = i * 16 + l15;
            const int rx  = row & 7;
            #pragma unroll
            for (int s = 0; s < 4; ++s) {
                const int pos = (s * 4 + lq) ^ rx;
                const short8 af = *(const short8*)&As[kt * (96*128) + row * 128 + pos * 8];
                acc[i][0] = __builtin_amdgcn_mfma_f32_16x16x32_bf16(af, bf[0][s], acc[i][0], 0, 0, 0);
                acc[i][1] = __builtin_amdgcn_mfma_f32_16x16x32_bf16(af, bf[1][s], acc[i][1], 0, 0, 0);
            }
        }
    }

    float attn0 = 0.f, attn1 = 0.f;
    float t00=0.f, t01=0.f, t02=0.f, t10=0.f, t11=0.f, t12=0.f;

    #pragma unroll
    for (int i = 0; i < 6; ++i) {
        #pragma unroll
        for (int rr = 0; rr < 4; ++rr) {
            const int m = i * 16 + lq * 4 + rr;
            const size_t krow = ((size_t)(b * Nn + m)) << 8;
            const float k0 = kmat[krow + dj0], k1 = kmat[krow + dj1];
            const float v0 = vmat[krow + dj0], v1 = vmat[krow + dj1];
            float pr = silu_f(acc[i][0][rr] + bv0) * k0 * qd0
                     + silu_f(acc[i][1][rr] + bv1) * k1 * qd1;
            #pragma unroll
            for (int off = 8; off; off >>= 1)
                pr += __shfl_xor(pr, off, 16);
            const float p = silu_f(pr) * scl[m];
            const float pv0 = p * v0, pv1 = p * v1;
            attn0 += pv0; attn1 += pv1;
            const float c0 = vcs[m][0], c1 = vcs[m][1], c2 = vcs[m][2];
            t00 = fmaf(c0, pv0, t00); t01 = fmaf(c1, pv0, t01); t02 = fmaf(c2, pv0, t02);
            t10 = fmaf(c0, pv1, t10); t11 = fmaf(c1, pv1, t11); t12 = fmaf(c2, pv1, t12);
        }
    }

    attn0 += __shfl_xor(attn0, 16, 64); attn0 += __shfl_xor(attn0, 32, 64);
    attn1 += __shfl_xor(attn1, 16, 64); attn1 += __shfl_xor(attn1, 32, 64);
    t00 += __shfl_xor(t00, 16, 64); t00 += __shfl_xor(t00, 32, 64);
    t01 += __shfl_xor(t01, 16, 64); t01 += __shfl_xor(t01, 32, 64);
    t02 += __shfl_xor(t02, 16, 64); t02 += __shfl_xor(t02, 32, 64);
    t10 += __shfl_xor(t10, 16, 64); t10 += __shfl_xor(t10, 32, 64);
    t11 += __shfl_xor(t11, 16, 64); t11 += __shfl_xor(t11, 32, 64);
    t12 += __shfl_xor(t12, 16, 64); t12 += __shfl_xor(t12, 32, 64);

    if (lq == 0) {
        attn_out[(size_t)bn * Dd + dj0] = attn0;
        attn_out[(size_t)bn * Dd + dj1] = attn1;
    }
    // wave-parallel sum of vec over unmasked m (3 waves, one per component)
    if (tid < 192) {
        const int c  = tid >> 6;
        const int ln = tid & 63;
        float s = 0.0f;
        for (int m = ln; m < Nn; m += 64)
            if (!mks[m]) s += vcs[m][c];
        #pragma unroll
        for (int off = 32; off; off >>= 1) s += __shfl_xor(s, off, 64);
        if (ln == 0) svs[c] = s;
    }

    // ---- fused du phase: As is dead -> LDS scratch (24.6 KB used of 48) ----
    __syncthreads();                       // all As reads + svs writes complete
    float* const sc   = (float*)As;
    float* const ts_  = sc;                // [3][256]  t rows
    float* const dup_ = sc + 768;          // [2][3][256] du partials
    float* const dus_ = sc + 2304;         // [3][256]
    float* const app_ = sc + 3072;         // [2][3][256] ws partials
    float* const atp_ = sc + 4608;         // [2][3][256] wt partials

    if (lq == 0) {
        ts_[0*256 + dj0] = t00; ts_[1*256 + dj0] = t01; ts_[2*256 + dj0] = t02;
        ts_[0*256 + dj1] = t10; ts_[1*256 + dj1] = t11; ts_[2*256 + dj1] = t12;
    }
    __syncthreads();

    const int d  = tid & 255;
    const int hf = tid >> 8;               // 0/1: split-k half
    const int kb = hf * 32;
    {
        float d0, d1, d2;
        if (hf == 0) {
            const float bd = bdu[d];
            d0 = svs[0] * bd; d1 = svs[1] * bd; d2 = svs[2] * bd;
        } else { d0 = d1 = d2 = 0.f; }
        for (int k4 = kb; k4 < kb + 32; ++k4) {
            const float w0 = Wdu[(size_t)(k4 * 4 + 0) * Dd + d];
            const float w1 = Wdu[(size_t)(k4 * 4 + 1) * Dd + d];
            const float w2 = Wdu[(size_t)(k4 * 4 + 2) * Dd + d];
            const float w3 = Wdu[(size_t)(k4 * 4 + 3) * Dd + d];
            const float4 e0 = *(const float4*)&ts_[0*256 + k4 * 4];
            const float4 e1 = *(const float4*)&ts_[1*256 + k4 * 4];
            const float4 e2 = *(const float4*)&ts_[2*256 + k4 * 4];
            d0 = fmaf(e0.x, w0, fmaf(e0.y, w1, fmaf(e0.z, w2, fmaf(e0.w, w3, d0))));
            d1 = fmaf(e1.x, w0, fmaf(e1.y, w1, fmaf(e1.z, w2, fmaf(e1.w, w3, d1))));
            d2 = fmaf(e2.x, w0, fmaf(e2.y, w1, fmaf(e2.z, w2, fmaf(e2.w, w3, d2))));
        }
        dup_[hf*768 + 0*256 + d] = d0;
        dup_[hf*768 + 1*256 + d] = d1;
        dup_[hf*768 + 2*256 + d] = d2;
    }
    __syncthreads();
    if (hf == 0) {
        #pragma unroll
        for (int j = 0; j < 3; ++j)
            dus_[j*256 + d] = dup_[j*256 + d] + dup_[768 + j*256 + d];
    }
    __syncthreads();
    {
        float a0=0.f,a1=0.f,a2=0.f, b0=0.f,b1=0.f,b2=0.f;
        for (int k4 = kb; k4 < kb + 32; ++k4) {
            const float s0 = Wdih[(size_t)(k4 * 4 + 0) * 512 + d];
            const float s1 = Wdih[(size_t)(k4 * 4 + 1) * 512 + d];
            const float s2 = Wdih[(size_t)(k4 * 4 + 2) * 512 + d];
            const float s3 = Wdih[(size_t)(k4 * 4 + 3) * 512 + d];
            const float u0 = Wdih[(size_t)(k4 * 4 + 0) * 512 + 256 + d];
            const float u1 = Wdih[(size_t)(k4 * 4 + 1) * 512 + 256 + d];
            const float u2 = Wdih[(size_t)(k4 * 4 + 2) * 512 + 256 + d];
            const float u3 = Wdih[(size_t)(k4 * 4 + 3) * 512 + 256 + d];
            const float4 e0 = *(const float4*)&dus_[0*256 + k4 * 4];
            const float4 e1 = *(const float4*)&dus_[1*256 + k4 * 4];
            const float4 e2 = *(const float4*)&dus_[2*256 + k4 * 4];
            a0 = fmaf(e0.x, s0, fmaf(e0.y, s1, fmaf(e0.z, s2, fmaf(e0.w, s3, a0))));
            a1 = fmaf(e1.x, s0, fmaf(e1.y, s1, fmaf(e1.z, s2, fmaf(e1.w, s3, a1))));
            a2 = fmaf(e2.x, s0, fmaf(e2.y, s1, fmaf(e2.z, s2, fmaf(e2.w, s3, a2))));
            b0 = fmaf(e0.x, u0, fmaf(e0.y, u1, fmaf(e0.z, u2, fmaf(e0.w, u3, b0))));
            b1 = fmaf(e1.x, u0, fmaf(e1.y, u1, fmaf(e1.z, u2, fmaf(e1.w, u3, b1))));
            b2 = fmaf(e2.x, u0, fmaf(e2.y, u1, fmaf(e2.z, u2, fmaf(e2.w, u3, b2))));
        }
        app_[hf*768 + 0*256 + d] = a0;
        app_[hf*768 + 1*256 + d] = a1;
        app_[hf*768 + 2*256 + d] = a2;
        atp_[hf*768 + 0*256 + d] = b0;
        atp_[hf*768 + 1*256 + d] = b1;
        atp_[hf*768 + 2*256 + d] = b2;
    }
    __syncthreads();
    if (hf == 0) {
        wsv[((size_t)bn * 3 + 0) * Dd + d] = app_[0*256 + d] + app_[768 + 0*256 + d];
        wsv[((size_t)bn * 3 + 1) * Dd + d] = app_[1*256 + d] + app_[768 + 1*256 + d];
        wsv[((size_t)bn * 3 + 2) * Dd + d] = app_[2*256 + d] + app_[768 + 2*256 + d];
        ushort4 pk;
        pk.x = (unsigned short)f2bf(atp_[0*256 + d] + atp_[768 + 0*256 + d]);
        pk.y = (unsigned short)f2bf(atp_[1*256 + d] + atp_[768 + 1*256 + d]);
        pk.z = (unsigned short)f2bf(atp_[2*256 + d] + atp_[768 + 2*256 + d]);
        pk.w = 0;
        *(ushort4*)(wtp + ((size_t)bn * Dd + d) * 4) = pk;
    }
}

// ---------------- Kernel 3: ipe = silu(edge@Wea + bea) * sum_c ws.wt (async-staged MFMA) ----------------
__global__ __launch_bounds__(512, 4) void ea_ipe_kernel(
    const unsigned short* __restrict__ ebf, const short* __restrict__ Wt,
    const float* __restrict__ bea,
    const float* __restrict__ wsv, const unsigned short* __restrict__ wtp,
    float* __restrict__ ipe)
{
    __shared__ short As[2 * 96 * 128];
    const int bn   = blockIdx.x;
    const int b    = bn / Nn;
    const int tid  = threadIdx.x;
    const int lane = tid & 63;
    const int w    = tid >> 6;
    const int l15  = lane & 15;
    const int lq   = lane >> 4;

    const int dj0 = w * 32 + l15, dj1 = dj0 + 16;
    const float be0 = bea[dj0], be1 = bea[dj1];
    const float ws00 = wsv[((size_t)bn*3+0)*Dd + dj0], ws01 = wsv[((size_t)bn*3+1)*Dd + dj0],
                ws02 = wsv[((size_t)bn*3+2)*Dd + dj0];
    const float ws10 = wsv[((size_t)bn*3+0)*Dd + dj1], ws11 = wsv[((size_t)bn*3+1)*Dd + dj1],
                ws12 = wsv[((size_t)bn*3+2)*Dd + dj1];

    f32x4 acc[6][2];
    #pragma unroll
    for (int i = 0; i < 6; ++i) { acc[i][0] = (f32x4){0.f,0.f,0.f,0.f}; acc[i][1] = (f32x4){0.f,0.f,0.f,0.f}; }

    const unsigned short* ebase = ebf + (size_t)bn * Nn * Dd;
    const int srow = (lane >> 4);
    const int cs   = lane & 15;

    #pragma unroll
    for (int kt = 0; kt < 2; ++kt) {
        #pragma unroll
        for (int u = 0; u < 3; ++u) {
            const int chunk = w * 3 + u;
            const int r     = chunk * 4 + srow;
            const int gseg  = cs ^ (r & 7);
            gll16(As + kt * (96*128) + chunk * 512,
                  ebase + (size_t)r * Dd + kt * 128 + gseg * 8);
        }
    }
    __syncthreads();

    #pragma unroll
    for (int kt = 0; kt < 2; ++kt) {
        short8 bf[2][4];
        #pragma unroll
        for (int s = 0; s < 4; ++s) {
            bf[0][s] = *(const short8*)(Wt + (size_t)dj0 * 256 + kt * 128 + s * 32 + lq * 8);
            bf[1][s] = *(const short8*)(Wt + (size_t)dj1 * 256 + kt * 128 + s * 32 + lq * 8);
        }
        #pragma unroll
        for (int i = 0; i < 6; ++i) {
            const int row = i * 16 + l15;
            const int rx  = row & 7;
            #pragma unroll
            for (int s = 0; s < 4; ++s) {
                const int pos = (s * 4 + lq) ^ rx;
                const short8 af = *(const short8*)&As[kt * (96*128) + row * 128 + pos * 8];
                acc[i][0] = __builtin_amdgcn_mfma_f32_16x16x32_bf16(af, bf[0][s], acc[i][0], 0, 0, 0);
                acc[i][1] = __builtin_amdgcn_mfma_f32_16x16x32_bf16(af, bf[1][s], acc[i][1], 0, 0, 0);
            }
        }
    }

    #pragma unroll
    for (int i = 0; i < 6; ++i) {
        #pragma unroll
        for (int rr = 0; rr < 4; ++rr) {
            const int m = i * 16 + lq * 4 + rr;
            const size_t wr = (size_t)(b * Nn + m);
            const ushort4 w40 = *(const ushort4*)(wtp + (wr * Dd + dj0) * 4);
            const ushort4 w41 = *(const ushort4*)(wtp + (wr * Dd + dj1) * 4);
            const float ea0 = silu_f(acc[i][0][rr] + be0);
            const float ea1 = silu_f(acc[i][1][rr] + be1);
            const float sd0 = ws00 * bf2f(w40.x) + ws01 * bf2f(w40.y) + ws02 * bf2f(w40.z);
            const float sd1 = ws10 * bf2f(w41.x) + ws11 * bf2f(w41.y) + ws12 * bf2f(w41.z);
            ipe[((size_t)bn * Nn + m) * Dd + dj0] = ea0 * sd0;
            ipe[((size_t)bn * Nn + m) * Dd + dj1] = ea1 * sd1;
        }
    }
}

extern "C" void kernel_launch(void* const* d_in, const int* in_sizes, int n_in,
                              void* d_out, int out_size, void* d_ws, size_t ws_size,
                              hipStream_t stream)
{
    const float* x    = (const float*)d_in[0];
    const float* vec  = (const float*)d_in[1];
    const float* dist = (const float*)d_in[2];
    const float* edge = (const float*)d_in[3];
    const int*   mask = (const int*)d_in[4];
    const float* Wq   = (const float*)d_in[5];
    const float* bq   = (const float*)d_in[6];
    const float* Wk   = (const float*)d_in[7];
    const float* bk   = (const float*)d_in[8];
    const float* Wv   = (const float*)d_in[9];
    const float* bv   = (const float*)d_in[10];
    const float* Wdk  = (const float*)d_in[11];
    const float* bdk  = (const float*)d_in[12];
    const float* Wdu  = (const float*)d_in[13];
    const float* bdu  = (const float*)d_in[14];
    const float* Wdih = (const float*)d_in[15];
    const float* Wea  = (const float*)d_in[16];
    const float* bea  = (const float*)d_in[17];

    float* out_attn = (float*)d_out;
    float* out_ipe  = out_attn + (size_t)BN * Dd;

    char* wsp = (char*)d_ws;
    unsigned short* ebf  = (unsigned short*)wsp;  wsp += (size_t)MT * Dd * 2;
    float* qb   = (float*)wsp;                    wsp += (size_t)BN * Dd * 4;
    float* kb   = (float*)wsp;                    wsp += (size_t)BN * Dd * 4;
    float* vb   = (float*)wsp;                    wsp += (size_t)BN * Dd * 4;
    float* wsvp = (float*)wsp;                    wsp += (size_t)BN * 3 * Dd * 4;
    unsigned short* wtpp = (unsigned short*)wsp;  wsp += (size_t)BN * Dd * 4 * 2;
    short* Wtdk = (short*)wsp;                    wsp += (size_t)Dd * Dd * 2;
    short* Wtea = (short*)wsp;                    wsp += (size_t)Dd * Dd * 2;

    setup_kernel<<<QKV_BLOCKS + WT_BLOCKS + PREP_BLOCKS, 256, 0, stream>>>(
        edge, ebf, Wdk, Wea, Wtdk, Wtea,
        x, Wq, bq, Wk, bk, Wv, bv, qb, kb, vb);
    dk_attn_kernel<<<BN, 512, 0, stream>>>(ebf, Wtdk, bdk, qb, kb, vb, mask, dist, vec,
                                           Wdu, bdu, Wdih,
                                           out_attn, wsvp, wtpp);
    ea_ipe_kernel<<<BN, 512, 0, stream>>>(ebf, Wtea, bea, wsvp, wtpp, out_ipe);
}